// Round 11
// baseline (807.575 us; speedup 1.0000x reference)
//
#include <hip/hip_runtime.h>
#include <hip/hip_bf16.h>
#include <cstdint>

#define B_   2
#define S_   2048
#define HID_ 3072
#define H_   16
#define KV_  8
#define D_   256
#define HD_  4096   // H_*D_
#define KVD_ 2048   // KV_*D_
#define QKS_ 8192   // merged qkv row stride

constexpr float EPS_   = 1e-6f;
constexpr float SCALE_ = 0.0625f;   // 256^-0.5

typedef unsigned short u16;
typedef __attribute__((ext_vector_type(8))) short bf16x8;
typedef __attribute__((ext_vector_type(4))) float f32x4;

__device__ inline float bf2f(u16 u) { return __uint_as_float(((unsigned int)u) << 16); }
__device__ inline u16 f2bf(float f) {
  unsigned int x = __float_as_uint(f);
  x += 0x7fffu + ((x >> 16) & 1u);   // RNE
  return (u16)(x >> 16);
}

// async global->LDS, 16B per lane; lds base must be wave-uniform, data lands at base + lane*16
__device__ inline void gll16(const u16* g, u16* l) {
  __builtin_amdgcn_global_load_lds((const __attribute__((address_space(1))) unsigned int*)g,
                                   (__attribute__((address_space(3))) unsigned int*)l,
                                   16, 0, 0);
}

// ---- device helper: transpose+cast tile, in[K][N] f32 -> out[N][K] bf16 ----
__device__ inline void tc_tile(const float* __restrict__ in, u16* __restrict__ out,
                               int K, int N, int bx, int by, int t) {
  __shared__ __align__(16) float tile[64][65];
  int n0 = bx * 64, k0 = by * 64;
  int rr = t >> 4, cc = (t & 15) * 4;
  for (int i = 0; i < 4; i++) {
    float4 v = *(const float4*)(&in[(size_t)(k0 + rr + 16 * i) * N + n0 + cc]);
    tile[rr + 16 * i][cc + 0] = v.x; tile[rr + 16 * i][cc + 1] = v.y;
    tile[rr + 16 * i][cc + 2] = v.z; tile[rr + 16 * i][cc + 3] = v.w;
  }
  __syncthreads();
  for (int i = 0; i < 4; i++) {
    int orow = rr + 16 * i;  // n index
    ushort4 o;
    o.x = f2bf(tile[cc + 0][orow]); o.y = f2bf(tile[cc + 1][orow]);
    o.z = f2bf(tile[cc + 2][orow]); o.w = f2bf(tile[cc + 3][orow]);
    *(ushort4*)(&out[(size_t)(n0 + orow) * K + k0 + cc]) = o;
  }
}

// ---- merged prep: cast hs + 4 weight transpose+casts, one launch ----
// blocks: [0,12288) cast; [12288,15360) qw; [15360,16896) kw; [16896,18432) vw;
//         [18432,21504) ow
__global__ void prep(const float* __restrict__ hs, u16* __restrict__ x_bf,
                     const float* __restrict__ qw, const float* __restrict__ kw,
                     const float* __restrict__ vw, const float* __restrict__ ow,
                     u16* __restrict__ wqkv_t, u16* __restrict__ ow_t) {
  int bid = blockIdx.x, t = threadIdx.x;
  if (bid < 12288) {
    int i = bid * 256 + t;
    float4 v = ((const float4*)hs)[i];
    ushort4 o;
    o.x = f2bf(v.x); o.y = f2bf(v.y); o.z = f2bf(v.z); o.w = f2bf(v.w);
    ((ushort4*)x_bf)[i] = o;
  } else if (bid < 15360) {
    int r = bid - 12288;                       // 64 x 48
    tc_tile(qw, wqkv_t, 3072, 4096, r % 64, r / 64, t);
  } else if (bid < 16896) {
    int r = bid - 15360;                       // 32 x 48
    tc_tile(kw, wqkv_t + (size_t)4096 * 3072, 3072, 2048, r % 32, r / 32, t);
  } else if (bid < 18432) {
    int r = bid - 16896;                       // 32 x 48
    tc_tile(vw, wqkv_t + (size_t)6144 * 3072, 3072, 2048, r % 32, r / 32, t);
  } else {
    int r = bid - 18432;                       // 48 x 64
    tc_tile(ow, ow_t, 4096, 3072, r % 48, r / 48, t);
  }
}

// ===== 256x256 8-wave GEMM, 1-barrier-per-tile free-run (round-7 best) =====
template <bool OUTF32>
__global__ __launch_bounds__(512, 2) void gemm256(const u16* __restrict__ A,
                                                  const u16* __restrict__ Bt,
                                                  void* __restrict__ Cv, int M, int N, int K) {
  __shared__ __align__(16) u16 As[2][16384];
  __shared__ __align__(16) u16 Bs[2][16384];
  int t = threadIdx.x, lane = t & 63, wave = t >> 6;
  int quad = lane >> 4, l16 = lane & 15;
  int wm = wave >> 2, wn = wave & 3;

  int nwg = gridDim.x * gridDim.y;
  int bid = blockIdx.y * gridDim.x + blockIdx.x;
  int sbid = (bid & 7) * (nwg >> 3) + (bid >> 3);
  int bn = (sbid % gridDim.x) * 256;
  int bm = (sbid / gridDim.x) * 256;

  int srow = lane >> 2;
  int scol8 = ((lane & 3) ^ ((lane >> 3) & 3)) * 8;
  const u16* ap = A + (size_t)(bm + srow) * K + scol8;
  const u16* bp = Bt + (size_t)(bn + srow) * K + scol8;
  int nr = (wave & 1) + ((wave >> 1) << 2);

  auto stA = [&](int sr, int sc, int k0, int bufi) {
    gll16(ap + (size_t)(sr * 16) * K + k0 + sc * 32, &As[bufi][(sr * 2 + sc) * 512]);
  };
  auto stB = [&](int sr, int sc, int k0, int bufi) {
    gll16(bp + (size_t)(sr * 16) * K + k0 + sc * 32, &Bs[bufi][(sr * 2 + sc) * 512]);
  };
  auto stageTile = [&](int kt, int bufi) {
    int k0 = kt * 64;
    stA(wave, 0, k0, bufi); stA(wave, 1, k0, bufi);
    stA(wave + 8, 0, k0, bufi); stA(wave + 8, 1, k0, bufi);
    stB(nr, 0, k0, bufi); stB(nr, 1, k0, bufi);
    stB(nr + 2, 0, k0, bufi); stB(nr + 2, 1, k0, bufi);
  };

  int rsw = l16 * 32 + ((quad ^ ((l16 >> 1) & 3)) * 8);
  auto LDA = [&](int bufi, int i, int ks) {
    return *(const bf16x8*)(&As[bufi][((wm * 8 + i) * 2 + ks) * 512 + rsw]);
  };
  auto LDB = [&](int bufi, int j, int ks) {
    return *(const bf16x8*)(&Bs[bufi][((wn * 4 + j) * 2 + ks) * 512 + rsw]);
  };

  f32x4 acc[8][4] = {};
  int NT = K >> 6;

  stageTile(0, 0);
  stageTile(1, 1);
  asm volatile("s_waitcnt vmcnt(8)" ::: "memory");
  __builtin_amdgcn_s_barrier();
  asm volatile("" ::: "memory");

  bf16x8 A0[4][2], A1[4][2], B01[2][2], B23[2][2];
#pragma unroll
  for (int j = 0; j < 2; j++) { B01[j][0] = LDB(0, j, 0); B01[j][1] = LDB(0, j, 1); }
#pragma unroll
  for (int i = 0; i < 4; i++) { A0[i][0] = LDA(0, i, 0); A0[i][1] = LDA(0, i, 1); }

#pragma unroll 1
  for (int kt = 0; kt < NT; kt++) {
    int cur = kt & 1, nxt = cur ^ 1;

#pragma unroll
    for (int i = 0; i < 4; i++) { A1[i][0] = LDA(cur, i + 4, 0); A1[i][1] = LDA(cur, i + 4, 1); }
    asm volatile("s_waitcnt lgkmcnt(8)" ::: "memory");
#pragma unroll
    for (int i = 0; i < 4; i++)
#pragma unroll
      for (int j = 0; j < 2; j++) {
        acc[i][j] = __builtin_amdgcn_mfma_f32_16x16x32_bf16(A0[i][0], B01[j][0], acc[i][j], 0, 0, 0);
        acc[i][j] = __builtin_amdgcn_mfma_f32_16x16x32_bf16(A0[i][1], B01[j][1], acc[i][j], 0, 0, 0);
      }
#pragma unroll
    for (int j = 0; j < 2; j++) { B23[j][0] = LDB(cur, j + 2, 0); B23[j][1] = LDB(cur, j + 2, 1); }
    asm volatile("s_waitcnt lgkmcnt(4)" ::: "memory");
#pragma unroll
    for (int i = 0; i < 4; i++)
#pragma unroll
      for (int j = 0; j < 2; j++) {
        acc[i + 4][j] = __builtin_amdgcn_mfma_f32_16x16x32_bf16(A1[i][0], B01[j][0], acc[i + 4][j], 0, 0, 0);
        acc[i + 4][j] = __builtin_amdgcn_mfma_f32_16x16x32_bf16(A1[i][1], B01[j][1], acc[i + 4][j], 0, 0, 0);
      }
    asm volatile("s_waitcnt lgkmcnt(0)" ::: "memory");
    asm volatile("s_waitcnt vmcnt(0)" ::: "memory");
    __builtin_amdgcn_s_barrier();
    asm volatile("" ::: "memory");
    if (kt + 2 < NT) stageTile(kt + 2, cur);
    __builtin_amdgcn_s_setprio(1);
#pragma unroll
    for (int i = 0; i < 4; i++)
#pragma unroll
      for (int j = 0; j < 2; j++) {
        acc[i][j + 2] = __builtin_amdgcn_mfma_f32_16x16x32_bf16(A0[i][0], B23[j][0], acc[i][j + 2], 0, 0, 0);
        acc[i][j + 2] = __builtin_amdgcn_mfma_f32_16x16x32_bf16(A0[i][1], B23[j][1], acc[i][j + 2], 0, 0, 0);
      }
    __builtin_amdgcn_s_setprio(0);
    if (kt + 1 < NT) {
#pragma unroll
      for (int j = 0; j < 2; j++) { B01[j][0] = LDB(nxt, j, 0); B01[j][1] = LDB(nxt, j, 1); }
    }
    __builtin_amdgcn_s_setprio(1);
#pragma unroll
    for (int i = 0; i < 4; i++)
#pragma unroll
      for (int j = 0; j < 2; j++) {
        acc[i + 4][j + 2] = __builtin_amdgcn_mfma_f32_16x16x32_bf16(A1[i][0], B23[j][0], acc[i + 4][j + 2], 0, 0, 0);
        acc[i + 4][j + 2] = __builtin_amdgcn_mfma_f32_16x16x32_bf16(A1[i][1], B23[j][1], acc[i + 4][j + 2], 0, 0, 0);
      }
    __builtin_amdgcn_s_setprio(0);
    if (kt + 1 < NT) {
#pragma unroll
      for (int i = 0; i < 4; i++) { A0[i][0] = LDA(nxt, i, 0); A0[i][1] = LDA(nxt, i, 1); }
    }
  }

#pragma unroll
  for (int i = 0; i < 8; i++)
#pragma unroll
    for (int j = 0; j < 4; j++)
#pragma unroll
      for (int r = 0; r < 4; r++) {
        int row = bm + wm * 128 + i * 16 + quad * 4 + r;
        int col = bn + wn * 64 + j * 16 + l16;
        float v = acc[i][j][r];
        if (OUTF32) ((float*)Cv)[(size_t)row * N + col] = v;
        else ((u16*)Cv)[(size_t)row * N + col] = f2bf(v);
      }
}

// ---- merged post-QKV: rmsnorm+rope (Q:4 ygroups, K:2) + transpose_v ----
// blocks [0,24576): rms (token = bid&4095, y = bid>>12, y<4 Q else K)
// blocks [24576,26624): transpose_v tile (r = bid-24576: 32 x 64)
__global__ void post_qkv(u16* __restrict__ xqkv, const float* __restrict__ qnw,
                         const float* __restrict__ knw, const float* __restrict__ fc,
                         const float* __restrict__ fsn, u16* __restrict__ vt) {
  int bid = blockIdx.x, t = threadIdx.x;
  if (bid < 24576) {
    int token = bid & 4095, y = bid >> 12;
    int lane = t & 63;
    const float* w;
    u16* p;
    float outscale;
    if (y < 4) { w = qnw; outscale = SCALE_;
      p = xqkv + (size_t)token * QKS_ + (y * 4 + (t >> 6)) * D_; }
    else { w = knw; outscale = 1.0f;
      p = xqkv + 4096 + (size_t)token * QKS_ + ((y - 4) * 4 + (t >> 6)) * D_; }
    int s = token & (S_ - 1);
    float v0 = bf2f(p[lane]);
    float v1 = bf2f(p[lane + 64]);
    float v2 = bf2f(p[lane + 128]);
    float v3 = bf2f(p[lane + 192]);
    float ss = v0 * v0 + v1 * v1 + v2 * v2 + v3 * v3;
    for (int off = 32; off; off >>= 1) ss += __shfl_xor(ss, off, 64);
    float rs = rsqrtf(ss * (1.0f / D_) + EPS_);
    float n0 = v0 * rs * (1.0f + w[lane]);
    float n1 = v1 * rs * (1.0f + w[lane + 64]);
    float n2 = v2 * rs * (1.0f + w[lane + 128]);
    float n3 = v3 * rs * (1.0f + w[lane + 192]);
    float c0 = fc[s * 128 + lane], s0 = fsn[s * 128 + lane];
    float c1 = fc[s * 128 + lane + 64], s1 = fsn[s * 128 + lane + 64];
    p[lane]       = f2bf((n0 * c0 - n2 * s0) * outscale);
    p[lane + 128] = f2bf((n0 * s0 + n2 * c0) * outscale);
    p[lane + 64]  = f2bf((n1 * c1 - n3 * s1) * outscale);
    p[lane + 192] = f2bf((n1 * s1 + n3 * c1) * outscale);
  } else {
    __shared__ __align__(16) u16 tile[64][68];
    int r = bid - 24576;
    int n0 = (r & 31) * 64, tk0 = (r >> 5) * 64;
    int b = tk0 >> 11, s0 = tk0 & (S_ - 1);
    int rr = t >> 4, cc = (t & 15) * 4;
    const u16* in = xqkv + 6144;
    for (int i = 0; i < 4; i++) {
      ushort4 v = *(const ushort4*)(&in[(size_t)(tk0 + rr + 16 * i) * QKS_ + n0 + cc]);
      tile[rr + 16 * i][cc + 0] = v.x; tile[rr + 16 * i][cc + 1] = v.y;
      tile[rr + 16 * i][cc + 2] = v.z; tile[rr + 16 * i][cc + 3] = v.w;
    }
    __syncthreads();
    for (int i = 0; i < 4; i++) {
      int orow = rr + 16 * i;
      ushort4 o;
      o.x = tile[cc + 0][orow]; o.y = tile[cc + 1][orow];
      o.z = tile[cc + 2][orow]; o.w = tile[cc + 3][orow];
      *(ushort4*)(&vt[((size_t)b << 22) + (size_t)(n0 + orow) * S_ + s0 + cc]) = o;
    }
  }
}

// ---------------- flash attention, causal, GQA rep=2, D=256 ----------------
// v5: 2 waves/block, 32 q-rows/wave (two 16-row groups sharing every K/V
// fragment read -> LDS read traffic per unit work halves). grid (16,16,2),
// causal pairing (66 iters uniform), 48KB LDS -> 3 blocks/CU. Staging:
// 8 K-gll16 + 8 V-gll16 per wave per tile; counted vmcnt(8) choreography.
__global__ __launch_bounds__(128, 2) void flash_attn(const u16* __restrict__ Q,
                                                     const u16* __restrict__ Kb,
                                                     const u16* __restrict__ Vt,
                                                     u16* __restrict__ O) {
  __shared__ __align__(16) u16 Ks[2][8 * 1024];   // [buf][chunk c][key 0..31][slot-swz 32 d]
  __shared__ __align__(16) u16 Vs[8 * 1024];      // [d 0..255][slot-swz 32 k]
  int t = threadIdx.x, lane = t & 63, wave = t >> 6;   // wave in {0,1}
  int quad = lane >> 4, l16 = lane & 15;
  int h = blockIdx.y, b = blockIdx.z;
  int kvh = h >> 1;

  int swz = ((lane & 3) ^ ((lane >> 2) & 3)) * 8;
  int rswz = (quad ^ (l16 & 3)) * 8;
  const u16* kst = Kb + (size_t)(b * S_ + (lane >> 2)) * QKS_ + kvh * D_ + wave * 128 + swz;
  const u16* vst = Vt + ((size_t)b << 22) + (size_t)(kvh * D_ + wave * 128 + (lane >> 2)) * S_ + swz;

  auto stageK = [&](int kt, int bufi) {   // 8 gll16: d-chunks 4w..4w+3, 2 key-rounds
    u16* kdst = &Ks[bufi][wave * 4096];
    const u16* ksrc = kst + (size_t)(kt * 32) * QKS_;
#pragma unroll
    for (int c2 = 0; c2 < 4; c2++)
#pragma unroll
      for (int r = 0; r < 2; r++)
        gll16(ksrc + (size_t)(r * 16) * QKS_ + c2 * 32, kdst + c2 * 1024 + r * 512);
  };
  auto stageV = [&](int kt) {             // 8 gll16: d rows w*128..w*128+127
    u16* vdst = &Vs[wave * 4096];
#pragma unroll
    for (int c = 0; c < 8; c++)
      gll16(vst + (size_t)(c * 16) * S_ + kt * 32, vdst + c * 512);
  };

#pragma unroll 1
  for (int half = 0; half < 2; half++) {
    int qb = (half == 0) ? (31 - (int)blockIdx.x) * 64 : (int)blockIdx.x * 64;
    int qw = qb + wave * 32;              // wave covers rows [qw, qw+32)

    bf16x8 qf[2][8];
#pragma unroll
    for (int g = 0; g < 2; g++) {
      const u16* qp = Q + ((size_t)(b * S_) + qw + g * 16 + l16) * QKS_ + h * D_;
#pragma unroll
      for (int c = 0; c < 8; c++) qf[g][c] = *(const bf16x8*)(qp + c * 32 + quad * 8);
    }

    f32x4 o_acc[2][16] = {};
    float m_s[2] = {-3e38f, -3e38f}, l_s[2] = {0.f, 0.f};

    int nkt = (qb + 64) >> 5;
    stageK(0, 0);
    stageV(0);
#pragma unroll 1
    for (int kt = 0; kt < nkt; kt++) {
      int cur = kt & 1;
      asm volatile("s_waitcnt vmcnt(8)" ::: "memory");   // K(kt) landed; V(kt) flies
      __builtin_amdgcn_s_barrier();
      asm volatile("" ::: "memory");
      if (kt + 1 < nkt) stageK(kt + 1, cur ^ 1);

      // ---- QK both groups, each K-fragment feeds 2 MFMAs ----
      f32x4 sc[2][2] = {};
#pragma unroll
      for (int c = 0; c < 8; c++) {
        bf16x8 k0 = *(const bf16x8*)(&Ks[cur][c * 1024 + l16 * 32 + rswz]);
        bf16x8 k1 = *(const bf16x8*)(&Ks[cur][c * 1024 + (l16 + 16) * 32 + rswz]);
        sc[0][0] = __builtin_amdgcn_mfma_f32_16x16x32_bf16(k0, qf[0][c], sc[0][0], 0, 0, 0);
        sc[0][1] = __builtin_amdgcn_mfma_f32_16x16x32_bf16(k1, qf[0][c], sc[0][1], 0, 0, 0);
        sc[1][0] = __builtin_amdgcn_mfma_f32_16x16x32_bf16(k0, qf[1][c], sc[1][0], 0, 0, 0);
        sc[1][1] = __builtin_amdgcn_mfma_f32_16x16x32_bf16(k1, qf[1][c], sc[1][1], 0, 0, 0);
      }

      // ---- softmax + in-register P butterfly, per group ----
      bf16x8 pf[2];
#pragma unroll
      for (int g = 0; g < 2; g++) {
        int qg = qw + g * 16 + l16;
        int kbase = kt * 32 + quad * 4;
        float p0[4], p1[4];
        float mx = -1e30f;
#pragma unroll
        for (int r = 0; r < 4; r++) {
          p0[r] = (kbase + r <= qg) ? sc[g][0][r] : -1e30f;
          p1[r] = (kbase + 16 + r <= qg) ? sc[g][1][r] : -1e30f;
          mx = fmaxf(mx, fmaxf(p0[r], p1[r]));
        }
        mx = fmaxf(mx, __shfl_xor(mx, 16));
        mx = fmaxf(mx, __shfl_xor(mx, 32));
        float mn = fmaxf(m_s[g], mx);
        bool chg = mn > m_s[g];
        float rsum = 0.f;
#pragma unroll
        for (int r = 0; r < 4; r++) {
          p0[r] = __expf(p0[r] - mn);
          p1[r] = __expf(p1[r] - mn);
          rsum += p0[r] + p1[r];
        }
        if (__any((int)chg)) {
          float alpha = __expf(m_s[g] - mn);
          float ar[4];
#pragma unroll
          for (int r = 0; r < 4; r++) ar[r] = __shfl(alpha, quad * 20 + r);
#pragma unroll
          for (int nt = 0; nt < 16; nt++)
#pragma unroll
            for (int r = 0; r < 4; r++) o_acc[g][nt][r] *= ar[r];
          l_s[g] *= alpha;
        }
        m_s[g] = mn;
        rsum += __shfl_xor(rsum, 16);
        rsum += __shfl_xor(rsum, 32);
        l_s[g] += rsum;

        unsigned int w_[4], x_[4], gl[4], gh[4], sn[4], rc[4];
        w_[0] = (unsigned)f2bf(p0[0]) | ((unsigned)f2bf(p0[1]) << 16);
        w_[1] = (unsigned)f2bf(p0[2]) | ((unsigned)f2bf(p0[3]) << 16);
        w_[2] = (unsigned)f2bf(p1[0]) | ((unsigned)f2bf(p1[1]) << 16);
        w_[3] = (unsigned)f2bf(p1[2]) | ((unsigned)f2bf(p1[3]) << 16);
#pragma unroll
        for (int i = 0; i < 4; i++) x_[i] = (unsigned)__shfl_xor((int)w_[i], 16);
        bool odd = (quad & 1) != 0;
        gl[0] = odd ? x_[0] : w_[0]; gl[1] = odd ? x_[1] : w_[1];
        gl[2] = odd ? w_[0] : x_[0]; gl[3] = odd ? w_[1] : x_[1];
        gh[0] = odd ? x_[2] : w_[2]; gh[1] = odd ? x_[3] : w_[3];
        gh[2] = odd ? w_[2] : x_[2]; gh[3] = odd ? w_[3] : x_[3];
#pragma unroll
        for (int i = 0; i < 4; i++) sn[i] = odd ? gl[i] : gh[i];
#pragma unroll
        for (int i = 0; i < 4; i++) rc[i] = (unsigned)__shfl_xor((int)sn[i], 32);
        union { unsigned int u[4]; bf16x8 v; } pfc;
#pragma unroll
        for (int i = 0; i < 4; i++)
          pfc.u[i] = (quad == 0) ? gl[i] : (quad == 3) ? gh[i] : rc[i];
        pf[g] = pfc.v;
      }

      // V(kt) landed (K(kt+1) may fly)
      if (kt + 1 < nkt) asm volatile("s_waitcnt vmcnt(8)" ::: "memory");
      else              asm volatile("s_waitcnt vmcnt(0)" ::: "memory");
      __builtin_amdgcn_s_barrier();
      asm volatile("" ::: "memory");

      // ---- PV both groups, each V-fragment feeds 2 MFMAs ----
#pragma unroll
      for (int nt = 0; nt < 16; nt++) {
        bf16x8 vf = *(const bf16x8*)(&Vs[(nt * 16 + l16) * 32 + rswz]);
        o_acc[0][nt] = __builtin_amdgcn_mfma_f32_16x16x32_bf16(pf[0], vf, o_acc[0][nt], 0, 0, 0);
        o_acc[1][nt] = __builtin_amdgcn_mfma_f32_16x16x32_bf16(pf[1], vf, o_acc[1][nt], 0, 0, 0);
      }

      asm volatile("s_waitcnt lgkmcnt(0)" ::: "memory");
      __builtin_amdgcn_s_barrier();
      asm volatile("" ::: "memory");
      if (kt + 1 < nkt) stageV(kt + 1);
    }

    // epilogue per group
#pragma unroll
    for (int g = 0; g < 2; g++) {
      float invl = 1.0f / l_s[g];
      float inv_r[4];
#pragma unroll
      for (int r = 0; r < 4; r++) inv_r[r] = __shfl(invl, quad * 20 + r);
      for (int r = 0; r < 4; r++) {
        int qg2 = qw + g * 16 + quad * 4 + r;
        u16* op = O + ((size_t)(b * S_) + qg2) * HD_ + h * D_;
        for (int nt = 0; nt < 16; nt++) op[nt * 16 + l16] = f2bf(o_acc[g][nt][r] * inv_r[r]);
      }
    }
  }
}

extern "C" void kernel_launch(void* const* d_in, const int* in_sizes, int n_in,
                              void* d_out, int out_size, void* d_ws, size_t ws_size,
                              hipStream_t stream) {
  const float* hs  = (const float*)d_in[0];
  const float* fc  = (const float*)d_in[1];
  const float* fsn = (const float*)d_in[2];
  // d_in[3] = mask: causal, replicated analytically
  const float* qw  = (const float*)d_in[4];
  const float* kw  = (const float*)d_in[5];
  const float* vw  = (const float*)d_in[6];
  const float* ow  = (const float*)d_in[7];
  const float* qnw = (const float*)d_in[8];
  const float* knw = (const float*)d_in[9];

  char* ws = (char*)d_ws;
  u16* x_bf   = (u16*)(ws + 0);          // 25165824 (dead after QKV GEMM)
  u16* vt     = (u16*)(ws + 0);          // 16777216 (overlays dead x_bf)
  u16* wqkv_t = (u16*)(ws + 25165824);   // [8192][3072] = 50331648
  u16* ow_t   = (u16*)(ws + 75497472);   // [3072][4096] = 25165824
  u16* xqkv   = (u16*)(ws + 100663296);  // [4096][8192] = 67108864 -> end 167772160
  u16* attn   = (u16*)(ws + 25165824);   // overlays dead wqkv_t after QKV GEMM

  prep<<<21504, 256, 0, stream>>>(hs, x_bf, qw, kw, vw, ow, wqkv_t, ow_t);

  // merged QKV projection: [4096][3072] x [8192][3072]^T -> [4096][8192]
  gemm256<false><<<dim3(32, 16), 512, 0, stream>>>(x_bf, wqkv_t, xqkv, 4096, 8192, 3072);

  post_qkv<<<26624, 256, 0, stream>>>(xqkv, qnw, knw, fc, fsn, vt);

  flash_attn<<<dim3(16, 16, 2), 128, 0, stream>>>(xqkv, xqkv + 4096, vt, attn);

  gemm256<true><<<dim3(12, 16), 512, 0, stream>>>(attn, ow_t, (float*)d_out, 4096, 3072, 4096);
}